// Round 12
// baseline (20.598 us; speedup 1.0000x reference)
//
#include <hip/hip_runtime.h>

#define TPB  1024          // 16 waves; 16 receivers per block
#define RPB  16
#define NMAX 4096          // max tokens (test: N=4096); LDS arrays sized to this
#define QCAP 128           // per-wave hit queue capacity (drain-on-overflow)

__device__ __forceinline__ float fpow_pos(float x, float p) {
    // x >= 0; pow via hardware log2/exp2. x==0 -> log2=-inf -> exp2(-inf)=0 (p>0).
    return __builtin_exp2f(p * __builtin_log2f(x));
}

// ONE node (R6/R7/R11 accounting: each graph node costs ~4 us; 2-node slice
// sort spent ~8-10 us on dispatch for ~5 us of work). Scan-compact-process:
// stage all tokens in LDS with a packed 16-bit cell code, integer-scan all
// N candidates (no transcendentals, no divergence), ballot-compact hits to a
// per-wave queue, then run the pow-chain ONCE, lane-parallel, on ~36 hits.
__global__ __launch_bounds__(TPB) void gwave_one(
    const float* __restrict__ ell, const float* __restrict__ theta,
    const float* __restrict__ fs, const float* __restrict__ mass,
    const unsigned char* __restrict__ frozen,
    const int* __restrict__ gsize_p, int n,
    float* __restrict__ out)
{
    __shared__ float s_e[NMAX];                 // 16 KB
    __shared__ float s_t[NMAX];                 // 16 KB
    __shared__ float s_f[NMAX];                 // 16 KB
    __shared__ unsigned short s_code[NMAX];     //  8 KB  (ce*64+ct; 0xFFFF = dead)
    __shared__ unsigned short s_q[TPB / 64][QCAP]; // 4 KB  per-wave hit queues

    const float PHI       = 1.61803398875f;
    const float INV_PHI   = 0.61803398875f;
    const float ONE_P_PHI = 2.61803398875f;
    const float TAU  = 6.2831855f;              // float32(2*pi)
    const float PI_F = 3.14159274f;             // float32(pi)
    const float EPS  = 1e-10f;

    const int tid  = threadIdx.x;
    const int lane = tid & 63;
    const int w    = tid >> 6;
    const int gs = *gsize_p;
    const float cw_ell = 2.0f / (float)gs;
    const float cw_th  = TAU  / (float)gs;

    // ---- stage all tokens into LDS (vectorized; code packs the cell) ----
    const int n4 = n >> 2;
    for (int b = tid; b < n4; b += TPB) {
        const float4 e4 = ((const float4*)ell)[b];
        const float4 t4 = ((const float4*)theta)[b];
        const float4 f4 = ((const float4*)fs)[b];
        const uchar4 z4 = ((const uchar4*)frozen)[b];
        const float  ee[4] = {e4.x, e4.y, e4.z, e4.w};
        const float  tt[4] = {t4.x, t4.y, t4.z, t4.w};
        const float  ff[4] = {f4.x, f4.y, f4.z, f4.w};
        const unsigned char zz[4] = {z4.x, z4.y, z4.z, z4.w};
        #pragma unroll
        for (int m = 0; m < 4; ++m) {
            const int r = (b << 2) + m;
            s_e[r] = ee[m]; s_t[r] = tt[m]; s_f[r] = ff[m];
            unsigned short code = 0xFFFF;
            if (!zz[m]) {
                int ce = min(max((int)floorf(ee[m] / cw_ell), 0), gs - 1);
                float tw = tt[m] - floorf(tt[m] / TAU) * TAU; // jnp.mod(t,TAU)
                int ct = min(max((int)floorf(tw / cw_th), 0), gs - 1);
                code = (unsigned short)((ce << 6) | ct);
            }
            s_code[r] = code;
        }
    }
    for (int r = (n4 << 2) + tid; r < n; r += TPB) {        // scalar tail
        s_e[r] = ell[r]; s_t[r] = theta[r]; s_f[r] = fs[r];
        unsigned short code = 0xFFFF;
        if (!frozen[r]) {
            int ce = min(max((int)floorf(s_e[r] / cw_ell), 0), gs - 1);
            float tw = s_t[r] - floorf(s_t[r] / TAU) * TAU;
            int ct = min(max((int)floorf(tw / cw_th), 0), gs - 1);
            code = (unsigned short)((ce << 6) | ct);
        }
        s_code[r] = code;
    }
    const int nn = (n + 63) & ~63;                          // pad to wave width
    if (tid < nn - n) s_code[n + tid] = 0xFFFF;
    __syncthreads();                                        // the only barrier

    // ---- one wave per receiver ----
    const int i = blockIdx.x * RPB + w;
    if (i >= n) return;                                     // after the barrier

    const unsigned short code_i = s_code[i];
    float Fe = 0.f, Ft = 0.f;

    if (code_i != 0xFFFF) {                                 // receiver active
        const int ce_i = code_i >> 6;
        const int ct_i = code_i & 63;
        const float e_i = s_e[i], t_i = s_t[i], f_i = s_f[i];
        const float m_i = mass[i];
        const float tp  = PI_F - t_i;
        unsigned short* qq = &s_q[w][0];
        int cnt = 0;                                        // wave-uniform

        // process the queued hits, lane-parallel (called with wave-uniform T)
        auto drain = [&](int T) {
            for (int b = 0; b < T; b += 64) {
                const int idx = b + lane;
                if (idx < T) {
                    const int q = qq[idx];
                    const float dl = s_e[q] - e_i;
                    // jnp.mod(dtheta+pi, tau)-pi; masked pairs never sit at
                    // the 0/tau rounding boundary (|dtheta| <= 2 cells), so
                    // the predicated wrap equals floor-mod.
                    float x = s_t[q] + tp;                  // in (-pi, 3pi)
                    x += (x < 0.f)  ? TAU : 0.f;
                    x -= (x >= TAU) ? TAU : 0.f;
                    const float dt = x - PI_F;
                    const float inner = fpow_pos(fabsf(dl), PHI)
                                      + fpow_pos(fabsf(dt), PHI);
                    const float dL = fpow_pos(inner, INV_PHI) + EPS;
                    const float fm = __fdividef(f_i * s_f[q],
                                        fpow_pos(dL, ONE_P_PHI) * m_i + EPS);
                    const float ww = fm * __fdividef(1.f, dL);
                    Fe += ww * dl;
                    Ft += ww * dt;
                }
            }
        };

        // integer scan of all candidates: ~15 VALU/iter, hits compacted
        for (int q0 = 0; q0 < nn; q0 += 64) {
            const int q = q0 + lane;
            const int code = s_code[q];
            const int u = (code >> 6) - ce_i + 1;           // dead codes fail u
            int v = (code & 63) - ct_i + 1;
            v += (v < 0)   ? gs : 0;
            v -= (v >= gs) ? gs : 0;
            const bool hit = ((unsigned)u <= 2u) & ((unsigned)v <= 2u)
                           & (q != i);
            const unsigned long long mask = __ballot(hit);
            if (mask) {                                     // wave-uniform
                if (hit) {
                    const int rank =
                        __popcll(mask & ((1ull << lane) - 1ull));
                    qq[cnt + rank] = (unsigned short)q;
                }
                cnt += __popcll(mask);
                if (cnt > QCAP - 64) { drain(cnt); cnt = 0; }   // uniform
            }
        }
        drain(cnt);                                         // final hits
    }

    // 64-lane butterfly reduce
    Fe += __shfl_xor(Fe, 1);
    Ft += __shfl_xor(Ft, 1);
    Fe += __shfl_xor(Fe, 2);
    Ft += __shfl_xor(Ft, 2);
    Fe += __shfl_xor(Fe, 4);
    Ft += __shfl_xor(Ft, 4);
    Fe += __shfl_xor(Fe, 8);
    Ft += __shfl_xor(Ft, 8);
    Fe += __shfl_xor(Fe, 16);
    Ft += __shfl_xor(Ft, 16);
    Fe += __shfl_xor(Fe, 32);
    Ft += __shfl_xor(Ft, 32);

    if (lane == 0) {                    // frozen receivers store 0
        out[i]     = Fe;
        out[n + i] = Ft;
    }
}

extern "C" void kernel_launch(void* const* d_in, const int* in_sizes, int n_in,
                              void* d_out, int out_size, void* d_ws, size_t ws_size,
                              hipStream_t stream) {
    const float* ell   = (const float*)d_in[0];
    const float* theta = (const float*)d_in[1];
    const float* fs    = (const float*)d_in[2];
    const float* mass  = (const float*)d_in[3];
    const unsigned char* frozen = (const unsigned char*)d_in[4];
    const int* gsize   = (const int*)d_in[5];
    float* out = (float*)d_out;
    const int n = in_sizes[0];          // assumed <= NMAX (test: 4096)

    const int blocks = (n + RPB - 1) / RPB;   // 256 at n=4096 — 1 per CU
    gwave_one<<<blocks, TPB, 0, stream>>>(
        ell, theta, fs, mass, frozen, gsize, n, out);
}

// Round 13
// 11.225 us; speedup vs baseline: 1.8350x; 1.8350x over previous
//
#include <hip/hip_runtime.h>

#define TPB  1024          // 16 waves; 16 receivers per block
#define RPB  16
#define NMAX 4096          // max tokens (test: N=4096)
#define MAXC 1024          // max cells (gs <= 32; test gs = 32); gs >= 4 for wrap
#define CAP  16            // bucket capacity; cnt>CAP cells -> exact fallback scan

__device__ __forceinline__ float fpow_pos(float x, float p) {
    // x >= 0; pow via hardware log2/exp2. x==0 -> log2=-inf -> exp2(-inf)=0 (p>0).
    return __builtin_exp2f(p * __builtin_log2f(x));
}

// ONE node. Per-block redundant BUCKET build (histogram only — no scan, no
// sorted scatter, one barrier), then depth-1 force: one wave per receiver,
// lane l -> (cell l/7, slot l%7) covers 9 cells x 7 slots in a single
// parallel step; ballot-guarded extra passes for slots 7..15; exact
// lane-strided fallback for cnt>CAP cells (prob ~1e-3, correctness only).
__global__ __launch_bounds__(TPB) void gwave_one(
    const float* __restrict__ ell, const float* __restrict__ theta,
    const float* __restrict__ fs, const float* __restrict__ mass,
    const unsigned char* __restrict__ frozen,
    const int* __restrict__ gsize_p, int n,
    float* __restrict__ out)
{
    __shared__ int s_cnt[MAXC];                    //  4 KB
    __shared__ unsigned short s_buck[MAXC][CAP];   // 32 KB (token ids)
    __shared__ unsigned short s_code[NMAX];        //  8 KB (cell id; 0xFFFF dead)

    const float PHI       = 1.61803398875f;
    const float INV_PHI   = 0.61803398875f;
    const float ONE_P_PHI = 2.61803398875f;
    const float TAU  = 6.2831855f;                 // float32(2*pi)
    const float PI_F = 3.14159274f;                // float32(pi)
    const float EPS  = 1e-10f;

    const int tid  = threadIdx.x;
    const int lane = tid & 63;
    const int w    = tid >> 6;
    const int gs = *gsize_p;
    const int C = gs * gs;                         // <= MAXC
    const float cw_ell = 2.0f / (float)gs;
    const float cw_th  = TAU  / (float)gs;

    // ---- Phase 1: zero counters, bucket all tokens (4/thread, vectorized) ----
    for (int c = tid; c < C; c += TPB) s_cnt[c] = 0;
    __syncthreads();

    const int n4 = n >> 2;
    for (int b = tid; b < n4; b += TPB) {
        const float4 e4 = ((const float4*)ell)[b];
        const float4 t4 = ((const float4*)theta)[b];
        const uchar4 z4 = ((const uchar4*)frozen)[b];
        const float ee[4] = {e4.x, e4.y, e4.z, e4.w};
        const float tt[4] = {t4.x, t4.y, t4.z, t4.w};
        const unsigned char zz[4] = {z4.x, z4.y, z4.z, z4.w};
        #pragma unroll
        for (int m = 0; m < 4; ++m) {
            const int r = (b << 2) + m;
            unsigned short code = 0xFFFF;
            if (!zz[m]) {
                int ce = min(max((int)floorf(ee[m] / cw_ell), 0), gs - 1);
                float tw = tt[m] - floorf(tt[m] / TAU) * TAU;  // jnp.mod(t,TAU)
                int ct = min(max((int)floorf(tw / cw_th), 0), gs - 1);
                const int c = ce * gs + ct;
                code = (unsigned short)c;
                const int pos = atomicAdd(&s_cnt[c], 1);
                if (pos < CAP) s_buck[c][pos] = (unsigned short)r;
            }
            s_code[r] = code;
        }
    }
    for (int r = (n4 << 2) + tid; r < n; r += TPB) {          // scalar tail
        unsigned short code = 0xFFFF;
        if (!frozen[r]) {
            const float e = ell[r], t = theta[r];
            int ce = min(max((int)floorf(e / cw_ell), 0), gs - 1);
            float tw = t - floorf(t / TAU) * TAU;
            int ct = min(max((int)floorf(tw / cw_th), 0), gs - 1);
            const int c = ce * gs + ct;
            code = (unsigned short)c;
            const int pos = atomicAdd(&s_cnt[c], 1);
            if (pos < CAP) s_buck[c][pos] = (unsigned short)r;
        }
        s_code[r] = code;
    }
    __syncthreads();                                          // the only barrier

    // ---- Phase 2: one wave per receiver ----
    const int i = blockIdx.x * RPB + w;
    if (i >= n) return;

    const unsigned short code_i = s_code[i];
    float Fe = 0.f, Ft = 0.f;

    if (code_i != 0xFFFF) {
        const int ce_i = (int)code_i / gs;
        const int ct_i = (int)code_i - ce_i * gs;
        const float e_i = ell[i], t_i = theta[i];
        const float f_i = fs[i],  m_i = mass[i];
        const float tp  = PI_F - t_i;

        // candidate chain (id != i checked by caller)
        auto chain = [&](int id) {
            const float dl = ell[id] - e_i;
            // jnp.mod(dtheta+pi, tau)-pi; masked pairs never sit at the
            // 0/tau rounding boundary (|dtheta| <= 2 cells), so the
            // predicated wrap equals floor-mod.
            float x = theta[id] + tp;                         // in (-pi, 3pi)
            x += (x < 0.f)  ? TAU : 0.f;
            x -= (x >= TAU) ? TAU : 0.f;
            const float dt = x - PI_F;
            const float inner = fpow_pos(fabsf(dl), PHI)
                              + fpow_pos(fabsf(dt), PHI);
            const float dL = fpow_pos(inner, INV_PHI) + EPS;
            const float fm = __fdividef(f_i * fs[id],
                                fpow_pos(dL, ONE_P_PHI) * m_i + EPS);
            const float ww = fm * __fdividef(1.f, dL);
            Fe += ww * dl;
            Ft += ww * dt;
        };

        // lane -> (neighbor cell k, slot)
        const int k    = lane / 7;            // 0..9 (lane 63: k=9, idle)
        const int slot = lane - k * 7;        // 0..6
        int c_k = -1, cnt = 0;
        if (k < 9) {
            const int kdiv = k / 3;
            const int ce = ce_i + kdiv - 1;                   // ell: no wrap
            if (ce >= 0 && ce < gs) {
                int ct = ct_i + (k - kdiv * 3) - 1;           // theta: wraps
                ct += (ct < 0)   ? gs : 0;
                ct -= (ct >= gs) ? gs : 0;
                c_k = ce * gs + ct;
                cnt = s_cnt[c_k];
            }
        }
        const bool cell_ok    = (c_k >= 0);
        const bool use_bucket = cell_ok && (cnt <= CAP);

        // bucket passes: slots [0,7), then ballot-guarded [7,14), [14,16)
        #pragma unroll
        for (int base = 0; base < CAP; base += 7) {
            if (base > 0) {
                const unsigned long long need =
                    __ballot(use_bucket && slot == 0 && cnt > base);
                if (!need) break;                             // wave-uniform
            }
            const int s2 = base + slot;
            if (use_bucket && s2 < cnt) {                     // s2 < cnt <= 16
                const int id = s_buck[c_k][s2];
                if (id != i) chain(id);
            }
        }

        // exact fallback for overflowed cells (cnt > CAP): whole-cell scan
        const unsigned long long oflow =
            __ballot(cell_ok && slot == 0 && cnt > CAP);
        if (oflow) {                                          // ~never taken
            for (int kk = 0; kk < 9; ++kk) {
                const int src  = kk * 7;
                const int cc   = __shfl(c_k, src);
                const int ccnt = __shfl(cnt, src);
                if (cc >= 0 && ccnt > CAP) {
                    for (int q = lane; q < n; q += 64) {
                        if ((int)s_code[q] == cc && q != i) chain(q);
                    }
                }
            }
        }
    }

    // 64-lane butterfly reduce
    Fe += __shfl_xor(Fe, 1);
    Ft += __shfl_xor(Ft, 1);
    Fe += __shfl_xor(Fe, 2);
    Ft += __shfl_xor(Ft, 2);
    Fe += __shfl_xor(Fe, 4);
    Ft += __shfl_xor(Ft, 4);
    Fe += __shfl_xor(Fe, 8);
    Ft += __shfl_xor(Ft, 8);
    Fe += __shfl_xor(Fe, 16);
    Ft += __shfl_xor(Ft, 16);
    Fe += __shfl_xor(Fe, 32);
    Ft += __shfl_xor(Ft, 32);

    if (lane == 0) {                          // frozen receivers store 0
        out[i]     = Fe;
        out[n + i] = Ft;
    }
}

extern "C" void kernel_launch(void* const* d_in, const int* in_sizes, int n_in,
                              void* d_out, int out_size, void* d_ws, size_t ws_size,
                              hipStream_t stream) {
    const float* ell   = (const float*)d_in[0];
    const float* theta = (const float*)d_in[1];
    const float* fs    = (const float*)d_in[2];
    const float* mass  = (const float*)d_in[3];
    const unsigned char* frozen = (const unsigned char*)d_in[4];
    const int* gsize   = (const int*)d_in[5];
    float* out = (float*)d_out;
    const int n = in_sizes[0];                // assumed <= NMAX (test: 4096)

    const int blocks = (n + RPB - 1) / RPB;   // 256 at n=4096 — 1 per CU
    gwave_one<<<blocks, TPB, 0, stream>>>(
        ell, theta, fs, mass, frozen, gsize, n, out);
}

// Round 14
// 10.697 us; speedup vs baseline: 1.9256x; 1.0493x over previous
//
#include <hip/hip_runtime.h>

#define TPB  1024          // 16 waves; 16 receivers per block
#define RPB  16
#define NMAX 4096          // max tokens (test: N=4096)
#define MAXC 1024          // max cells (gs <= 32; test gs = 32); gs >= 4 for wrap
#define CAP  16            // bucket capacity; cnt>CAP cells -> exact fallback scan

__device__ __forceinline__ float fpow_pos(float x, float p) {
    // x >= 0; pow via hardware log2/exp2. x==0 -> log2=-inf -> exp2(-inf)=0 (p>0).
    return __builtin_exp2f(p * __builtin_log2f(x));
}

// ONE node; per-block redundant bucket build (R13), slimmed:
//  - ell cell: e/(2/gs) == e*(gs/2) EXACTLY when gs is pow2 (2/gs = 2^-k)
//  - theta mod: floor(t/TAU)==0 for t in [0,TAU) -> tw = t, bit-exact; the
//    divide path survives for out-of-range inputs
//  - no s_code array, no fs staging load (fs gathered in phase 2 only)
__global__ __launch_bounds__(TPB) void gwave_one(
    const float* __restrict__ ell, const float* __restrict__ theta,
    const float* __restrict__ fs, const float* __restrict__ mass,
    const unsigned char* __restrict__ frozen,
    const int* __restrict__ gsize_p, int n,
    float* __restrict__ out)
{
    __shared__ int s_cnt[MAXC];                    //  4 KB
    __shared__ unsigned short s_buck[MAXC][CAP];   // 32 KB (token ids)

    const float PHI       = 1.61803398875f;
    const float INV_PHI   = 0.61803398875f;
    const float ONE_P_PHI = 2.61803398875f;
    const float TAU  = 6.2831855f;                 // float32(2*pi)
    const float PI_F = 3.14159274f;                // float32(pi)
    const float EPS  = 1e-10f;

    const int tid  = threadIdx.x;
    const int lane = tid & 63;
    const int w    = tid >> 6;
    const int gs = *gsize_p;
    const int C = gs * gs;                         // <= MAXC
    const bool pow2   = (gs & (gs - 1)) == 0;
    const float mule  = (float)gs * 0.5f;          // 1/cw_ell, exact iff pow2
    const float cw_ell = 2.0f / (float)gs;
    const float cw_th  = TAU  / (float)gs;

    // cell coords (bit-exact vs reference for all inputs)
    auto cell_ce = [&](float e) -> int {
        const float q = pow2 ? e * mule : e / cw_ell;
        return min(max((int)floorf(q), 0), gs - 1);
    };
    auto cell_ct = [&](float t) -> int {
        float tw = t;
        if (!(t >= 0.f && t < TAU))                // rare path: exact floor-mod
            tw = t - floorf(t / TAU) * TAU;
        return min(max((int)floorf(tw / cw_th), 0), gs - 1);
    };

    // ---- Phase 1: zero counters, bucket all tokens (4/thread, vectorized) ----
    for (int c = tid; c < C; c += TPB) s_cnt[c] = 0;
    __syncthreads();

    const int n4 = n >> 2;
    for (int b = tid; b < n4; b += TPB) {
        const float4 e4 = ((const float4*)ell)[b];
        const float4 t4 = ((const float4*)theta)[b];
        const uchar4 z4 = ((const uchar4*)frozen)[b];
        const float ee[4] = {e4.x, e4.y, e4.z, e4.w};
        const float tt[4] = {t4.x, t4.y, t4.z, t4.w};
        const unsigned char zz[4] = {z4.x, z4.y, z4.z, z4.w};
        #pragma unroll
        for (int m = 0; m < 4; ++m) {
            if (!zz[m]) {
                const int c = cell_ce(ee[m]) * gs + cell_ct(tt[m]);
                const int pos = atomicAdd(&s_cnt[c], 1);
                if (pos < CAP) s_buck[c][pos] = (unsigned short)((b << 2) + m);
            }
        }
    }
    for (int r = (n4 << 2) + tid; r < n; r += TPB) {          // scalar tail
        if (!frozen[r]) {
            const int c = cell_ce(ell[r]) * gs + cell_ct(theta[r]);
            const int pos = atomicAdd(&s_cnt[c], 1);
            if (pos < CAP) s_buck[c][pos] = (unsigned short)r;
        }
    }
    __syncthreads();                                          // the only barrier

    // ---- Phase 2: one wave per receiver ----
    const int i = blockIdx.x * RPB + w;
    if (i >= n) return;

    float Fe = 0.f, Ft = 0.f;
    if (!frozen[i]) {
        const float e_i = ell[i], t_i = theta[i];
        const float f_i = fs[i],  m_i = mass[i];
        const int ce_i = cell_ce(e_i);
        const int ct_i = cell_ct(t_i);
        const float tp = PI_F - t_i;

        // candidate chain (id != i checked by caller)
        auto chain = [&](int id) {
            const float dl = ell[id] - e_i;
            // jnp.mod(dtheta+pi, tau)-pi via predicated wrap: x in (-pi,3pi),
            // floor(x/TAU) is -1/0/1 exactly, so +-TAU matches floor-mod
            // bit-for-bit (Sterbenz: the subtraction is exact).
            float x = theta[id] + tp;
            x += (x < 0.f)  ? TAU : 0.f;
            x -= (x >= TAU) ? TAU : 0.f;
            const float dt = x - PI_F;
            const float inner = fpow_pos(fabsf(dl), PHI)
                              + fpow_pos(fabsf(dt), PHI);
            const float dL = fpow_pos(inner, INV_PHI) + EPS;
            const float fm = __fdividef(f_i * fs[id],
                                fpow_pos(dL, ONE_P_PHI) * m_i + EPS);
            const float ww = fm * __fdividef(1.f, dL);
            Fe += ww * dl;
            Ft += ww * dt;
        };

        // lane -> (neighbor cell k, slot)
        const int k    = lane / 7;            // 0..9 (lane 63: k=9, idle)
        const int slot = lane - k * 7;        // 0..6
        int c_k = -1, cnt = 0;
        if (k < 9) {
            const int kdiv = k / 3;
            const int ce = ce_i + kdiv - 1;                   // ell: no wrap
            if (ce >= 0 && ce < gs) {
                int ct = ct_i + (k - kdiv * 3) - 1;           // theta: wraps
                ct += (ct < 0)   ? gs : 0;
                ct -= (ct >= gs) ? gs : 0;
                c_k = ce * gs + ct;
                cnt = s_cnt[c_k];
            }
        }
        const bool cell_ok    = (c_k >= 0);
        const bool use_bucket = cell_ok && (cnt <= CAP);

        // bucket passes: slots [0,7), then ballot-guarded [7,14), [14,16)
        #pragma unroll
        for (int base = 0; base < CAP; base += 7) {
            if (base > 0) {
                const unsigned long long need =
                    __ballot(use_bucket && slot == 0 && cnt > base);
                if (!need) break;                             // wave-uniform
            }
            const int s2 = base + slot;
            if (use_bucket && s2 < cnt) {                     // s2 < cnt <= 16
                const int id = s_buck[c_k][s2];
                if (id != i) chain(id);
            }
        }

        // exact fallback for overflowed cells (cnt > CAP): whole-cell rescan
        const unsigned long long oflow =
            __ballot(cell_ok && slot == 0 && cnt > CAP);
        if (oflow) {                                          // ~never taken
            for (int kk = 0; kk < 9; ++kk) {
                const int src  = kk * 7;
                const int cc   = __shfl(c_k, src);
                const int ccnt = __shfl(cnt, src);
                if (cc >= 0 && ccnt > CAP) {
                    for (int q = lane; q < n; q += 64) {
                        if (q != i && !frozen[q]) {
                            const int cq = cell_ce(ell[q]) * gs
                                         + cell_ct(theta[q]);
                            if (cq == cc) chain(q);
                        }
                    }
                }
            }
        }
    }

    // 64-lane butterfly reduce
    Fe += __shfl_xor(Fe, 1);
    Ft += __shfl_xor(Ft, 1);
    Fe += __shfl_xor(Fe, 2);
    Ft += __shfl_xor(Ft, 2);
    Fe += __shfl_xor(Fe, 4);
    Ft += __shfl_xor(Ft, 4);
    Fe += __shfl_xor(Fe, 8);
    Ft += __shfl_xor(Ft, 8);
    Fe += __shfl_xor(Fe, 16);
    Ft += __shfl_xor(Ft, 16);
    Fe += __shfl_xor(Fe, 32);
    Ft += __shfl_xor(Ft, 32);

    if (lane == 0) {                          // frozen receivers store 0
        out[i]     = Fe;
        out[n + i] = Ft;
    }
}

extern "C" void kernel_launch(void* const* d_in, const int* in_sizes, int n_in,
                              void* d_out, int out_size, void* d_ws, size_t ws_size,
                              hipStream_t stream) {
    const float* ell   = (const float*)d_in[0];
    const float* theta = (const float*)d_in[1];
    const float* fs    = (const float*)d_in[2];
    const float* mass  = (const float*)d_in[3];
    const unsigned char* frozen = (const unsigned char*)d_in[4];
    const int* gsize   = (const int*)d_in[5];
    float* out = (float*)d_out;
    const int n = in_sizes[0];                // assumed <= NMAX (test: 4096)

    const int blocks = (n + RPB - 1) / RPB;   // 256 at n=4096 — 1 per CU
    gwave_one<<<blocks, TPB, 0, stream>>>(
        ell, theta, fs, mass, frozen, gsize, n, out);
}